// Round 1
// baseline (694.838 us; speedup 1.0000x reference)
//
#include <hip/hip_runtime.h>
#include <hip/hip_bf16.h>
#include <math.h>

// Problem constants (from reference): B=2, T=4096, N=8, D=2048, EPS=1e-6, TEMP=1
#define NROWS 8
#define DIM   2048
#define EPSV  1e-6f

// One block of 256 threads per (b,t) position.
// Each thread owns 8 d-elements (two float4 chunks: d0 = tid*4, d1 = 1024 + tid*4)
// of ALL 8 rows -> 64 floats of row payload in registers. Single pass over HBM.
__global__ __launch_bounds__(256) void block_attn_route(
    const float* __restrict__ src,      // [BT, NROWS, DIM]
    const float* __restrict__ w_query,  // [DIM]
    const float* __restrict__ norm_w,   // [DIM]
    float* __restrict__ out)            // [BT, DIM]
{
    const int bt  = blockIdx.x;
    const int tid = threadIdx.x;
    const int d0  = tid * 4;          // 0..1023
    const int d1  = 1024 + tid * 4;   // 1024..2047

    const float* base = src + (size_t)bt * (NROWS * DIM);

    // effective query = w_query * norm_weight (broadcast loads, L2-resident)
    float4 wq0 = *(const float4*)(w_query + d0);
    float4 wq1 = *(const float4*)(w_query + d1);
    float4 nw0 = *(const float4*)(norm_w + d0);
    float4 nw1 = *(const float4*)(norm_w + d1);
    float4 q0, q1;
    q0.x = wq0.x * nw0.x; q0.y = wq0.y * nw0.y; q0.z = wq0.z * nw0.z; q0.w = wq0.w * nw0.w;
    q1.x = wq1.x * nw1.x; q1.y = wq1.y * nw1.y; q1.z = wq1.z * nw1.z; q1.w = wq1.w * nw1.w;

    float4 s0[NROWS], s1[NROWS];
    float sumsq[NROWS], dotq[NROWS];

    #pragma unroll
    for (int n = 0; n < NROWS; ++n) {
        const float* rp = base + n * DIM;
        s0[n] = *(const float4*)(rp + d0);
        s1[n] = *(const float4*)(rp + d1);
        float ss = s0[n].x * s0[n].x + s0[n].y * s0[n].y
                 + s0[n].z * s0[n].z + s0[n].w * s0[n].w
                 + s1[n].x * s1[n].x + s1[n].y * s1[n].y
                 + s1[n].z * s1[n].z + s1[n].w * s1[n].w;
        float dt = s0[n].x * q0.x + s0[n].y * q0.y
                 + s0[n].z * q0.z + s0[n].w * q0.w
                 + s1[n].x * q1.x + s1[n].y * q1.y
                 + s1[n].z * q1.z + s1[n].w * q1.w;
        sumsq[n] = ss;
        dotq[n]  = dt;
    }

    // Wave-level butterfly reduction of 16 partials (8 rows x {sumsq, dot}).
    #pragma unroll
    for (int n = 0; n < NROWS; ++n) {
        #pragma unroll
        for (int off = 32; off >= 1; off >>= 1) {
            sumsq[n] += __shfl_xor(sumsq[n], off, 64);
            dotq[n]  += __shfl_xor(dotq[n],  off, 64);
        }
    }

    // Cross-wave combine via tiny LDS buffer: [16 values][4 waves]
    __shared__ float red[16][4];
    const int wave = tid >> 6;
    const int lane = tid & 63;
    if (lane == 0) {
        #pragma unroll
        for (int n = 0; n < NROWS; ++n) {
            red[n][wave]         = sumsq[n];
            red[n + NROWS][wave] = dotq[n];
        }
    }
    __syncthreads();

    // Every thread redundantly computes the 8 scores + softmax (broadcast LDS reads).
    const float inv_d      = 1.0f / (float)DIM;
    const float inv_sqrt_d = 0.022097086912079608f;  // 1/sqrt(2048)
    float scores[NROWS];
    #pragma unroll
    for (int n = 0; n < NROWS; ++n) {
        float ss = red[n][0] + red[n][1] + red[n][2] + red[n][3];
        float dt = red[n + NROWS][0] + red[n + NROWS][1] + red[n + NROWS][2] + red[n + NROWS][3];
        float inv_rms = rsqrtf(ss * inv_d + EPSV);
        scores[n] = dt * inv_rms * inv_sqrt_d;
    }

    float m = scores[0];
    #pragma unroll
    for (int n = 1; n < NROWS; ++n) m = fmaxf(m, scores[n]);
    float w[NROWS];
    float wsum = 0.0f;
    #pragma unroll
    for (int n = 0; n < NROWS; ++n) {
        w[n] = __expf(scores[n] - m);
        wsum += w[n];
    }
    const float inv_wsum = 1.0f / wsum;

    // Thread-local weighted combine of the register-resident rows.
    float4 o0 = make_float4(0.f, 0.f, 0.f, 0.f);
    float4 o1 = make_float4(0.f, 0.f, 0.f, 0.f);
    #pragma unroll
    for (int n = 0; n < NROWS; ++n) {
        const float wn = w[n] * inv_wsum;
        o0.x += wn * s0[n].x; o0.y += wn * s0[n].y;
        o0.z += wn * s0[n].z; o0.w += wn * s0[n].w;
        o1.x += wn * s1[n].x; o1.y += wn * s1[n].y;
        o1.z += wn * s1[n].z; o1.w += wn * s1[n].w;
    }

    float* op = out + (size_t)bt * DIM;
    *(float4*)(op + d0) = o0;
    *(float4*)(op + d1) = o1;
}

extern "C" void kernel_launch(void* const* d_in, const int* in_sizes, int n_in,
                              void* d_out, int out_size, void* d_ws, size_t ws_size,
                              hipStream_t stream) {
    const float* src = (const float*)d_in[0];   // [B,T,N,D] fp32
    const float* wq  = (const float*)d_in[1];   // [D]
    const float* nw  = (const float*)d_in[2];   // [D]
    float* out       = (float*)d_out;           // [B,T,D] fp32

    const int bt = in_sizes[0] / (NROWS * DIM); // B*T = 8192
    block_attn_route<<<bt, 256, 0, stream>>>(src, wq, nw, out);
}